// Round 21
// baseline (916.257 us; speedup 1.0000x reference)
//
#include <hip/hip_runtime.h>
#include <math.h>
#include <float.h>

#define EPSV 1e-8f
constexpr int D = 64;

typedef __attribute__((ext_vector_type(8)))  short short8;
typedef __attribute__((ext_vector_type(16))) float f32x16;

static __device__ __forceinline__ unsigned short f2bf(float f) {
    unsigned u = __float_as_uint(f);
    unsigned r = u + 0x7FFFu + ((u >> 16) & 1u);   // round-to-nearest-even
    return (unsigned short)(r >> 16);
}
static __device__ __forceinline__ float bf2f(unsigned short b) {
    return __uint_as_float(((unsigned)b) << 16);
}
static __device__ __forceinline__ unsigned umin2(unsigned a, unsigned b) { return a < b ? a : b; }
static __device__ __forceinline__ unsigned umax2(unsigned a, unsigned b) { return a > b ? a : b; }

// fragment-ready layout: entity panel p=e>>5, k-slot q=k>>3:
//   u16 index = p*2048 + q*256 + (e&31)*8 + (k&7)
static __device__ __forceinline__ size_t fragidx(int e, int k) {
    return (size_t)(e >> 5) * 2048 + (size_t)(k >> 3) * 256 + (e & 31) * 8 + (k & 7);
}

// ---------------------------------------------------------------------------
// prep (fused): blocks [0, K/4) normalize codebook rows; blocks [K/4, ...)
// normalize x rows (xn + hi/lo fragments). Also zeroes fixcnt.
// ---------------------------------------------------------------------------
__global__ __launch_bounds__(256) void k_prep(const float* __restrict__ cbin,
                                              float* __restrict__ cb,
                                              unsigned short* __restrict__ ch,
                                              unsigned short* __restrict__ cl,
                                              const float* __restrict__ xin,
                                              float* __restrict__ xn,
                                              unsigned short* __restrict__ xh,
                                              unsigned short* __restrict__ xl,
                                              int* __restrict__ fixcnt,
                                              int nbcb) {
    const int t = threadIdx.x;
    if (blockIdx.x == 0 && t == 0) *fixcnt = 0;
    const int wv = t >> 6, lane = t & 63;
    if ((int)blockIdx.x < nbcb) {
        const int code = blockIdx.x * 4 + wv;
        float v = cbin[(size_t)code * D + lane];
        float ss = v * v;
        #pragma unroll
        for (int off = 32; off; off >>= 1) ss += __shfl_xor(ss, off, 64);
        const float c1 = v / (sqrtf(ss) + EPSV);
        cb[(size_t)code * D + lane] = c1;
        float ss2 = c1 * c1;
        #pragma unroll
        for (int off = 32; off; off >>= 1) ss2 += __shfl_xor(ss2, off, 64);
        const float c2 = c1 / (sqrtf(ss2) + EPSV);
        const unsigned short h = f2bf(c2);
        const size_t fi = fragidx(code, lane);
        ch[fi] = h;
        cl[fi] = f2bf(c2 - bf2f(h));
    } else {
        const int row = (blockIdx.x - nbcb) * 4 + wv;
        float v = xin[(size_t)row * D + lane];
        float ss = v * v;
        #pragma unroll
        for (int off = 32; off; off >>= 1) ss += __shfl_xor(ss, off, 64);
        const float xv = v / (sqrtf(ss) + EPSV);
        xn[(size_t)row * D + lane] = xv;
        const unsigned short h = f2bf(xv);
        const size_t fi = fragidx(row, lane);
        xh[fi] = h;
        xl[fi] = f2bf(xv - bf2f(h));
    }
}

// ---------------------------------------------------------------------------
// main: 128 rows x 2048 codes per block (32 tiles of 64 codes), 4 waves.
// MASK-FREE: pure GEMM + per-lane top-2 of key=(q<<14)|code (u32-min).
// Swapped MFMA (A=codes, B=x-rows): acc col = x-row -> lane-local argmin.
// Code fragments staged to LDS once per BLOCK (shared by 4 waves ->
// 4x less L2 traffic), double-buffered via global_load_lds.
// ---------------------------------------------------------------------------
__global__ __launch_bounds__(256, 4) void k_mfma(const unsigned short* __restrict__ xh,
                                                 const unsigned short* __restrict__ xl,
                                                 const unsigned short* __restrict__ ch,
                                                 const unsigned short* __restrict__ cl,
                                                 unsigned* __restrict__ pk1,
                                                 unsigned* __restrict__ pk2,
                                                 int B, int K) {
    __shared__ short8 lch[2][2][256];            // 16 KB: [buf][panel][frag]
    __shared__ short8 lcl[2][2][256];            // 16 KB
    const int t = threadIdx.x;
    const int wv = t >> 6, lane = t & 63;
    const int lh = lane >> 5, lm = lane & 31;
    const int ks = (int)(blockIdx.x & 7);        // k-split (XCD-affine slice)
    const int rb = (int)(blockIdx.x >> 3);
    const int lh4 = lh * 4;

    const short8* xh8 = (const short8*)xh;
    const short8* xl8 = (const short8*)xl;
    const short8* ch8 = (const short8*)ch;
    const short8* cl8 = (const short8*)cl;

    const int rp = rb * 4 + wv;                  // this wave's 32-row panel
    const int row = rp * 32 + lm;                // this lane's x-row

    // B fragments (x rows), held for the whole block
    short8 bh[4], bl[4];
    #pragma unroll
    for (int s = 0; s < 4; ++s) {
        const size_t bi = (size_t)rp * 256 + (s * 2 + lh) * 32 + lm;
        bh[s] = xh8[bi];
        bl[s] = xl8[bi];
    }

    // stage tile tt_'s ch/cl fragments (2 panels) into buffer b_
#define STAGE(b_, tt_) do {                                                    \
    const int ct_ = ks * 32 + (tt_);                                           \
    const short8* s0 = ch8 + (size_t)(ct_ * 2 + 0) * 256 + t;                  \
    const short8* s1 = ch8 + (size_t)(ct_ * 2 + 1) * 256 + t;                  \
    const short8* s2 = cl8 + (size_t)(ct_ * 2 + 0) * 256 + t;                  \
    const short8* s3 = cl8 + (size_t)(ct_ * 2 + 1) * 256 + t;                  \
    __builtin_amdgcn_global_load_lds(                                          \
        (const __attribute__((address_space(1))) void*)s0,                     \
        (__attribute__((address_space(3))) void*)(&lch[b_][0][wv * 64]), 16, 0, 0); \
    __builtin_amdgcn_global_load_lds(                                          \
        (const __attribute__((address_space(1))) void*)s1,                     \
        (__attribute__((address_space(3))) void*)(&lch[b_][1][wv * 64]), 16, 0, 0); \
    __builtin_amdgcn_global_load_lds(                                          \
        (const __attribute__((address_space(1))) void*)s2,                     \
        (__attribute__((address_space(3))) void*)(&lcl[b_][0][wv * 64]), 16, 0, 0); \
    __builtin_amdgcn_global_load_lds(                                          \
        (const __attribute__((address_space(1))) void*)s3,                     \
        (__attribute__((address_space(3))) void*)(&lcl[b_][1][wv * 64]), 16, 0, 0); \
} while (0)

    unsigned k1 = 0xFFFFFFFFu, k2 = 0xFFFFFFFFu;

    STAGE(0, 0);

    #pragma unroll 1
    for (int tt = 0; tt < 32; ++tt) {
        __syncthreads();                         // drains stage(tt) (vmcnt)
        if (tt < 31) STAGE((tt + 1) & 1, tt + 1);
        const int bsel = tt & 1;
        const int ct = ks * 32 + tt;             // global 64-code tile id

        #pragma unroll
        for (int p = 0; p < 2; ++p) {
            short8 ah[4], al[4];
            #pragma unroll
            for (int s = 0; s < 4; ++s) {
                const int ai = (s * 2 + lh) * 32 + lm;
                ah[s] = lch[bsel][p][ai];
                al[s] = lcl[bsel][p][ai];
            }
            f32x16 acc;
            #pragma unroll
            for (int i = 0; i < 16; ++i) acc[i] = 0.f;
            #pragma unroll
            for (int s = 0; s < 4; ++s) {
                acc = __builtin_amdgcn_mfma_f32_32x32x16_bf16(ah[s], bh[s], acc, 0, 0, 0);
                acc = __builtin_amdgcn_mfma_f32_32x32x16_bf16(ah[s], bl[s], acc, 0, 0, 0);
                acc = __builtin_amdgcn_mfma_f32_32x32x16_bf16(al[s], bh[s], acc, 0, 0, 0);
            }
            const unsigned kbase = (unsigned)(ct * 64 + p * 32 + lh4);
            #pragma unroll
            for (int r = 0; r < 16; ++r) {
                const int base = (r & 3) + 8 * (r >> 2);              // static
                const float qf = fmaf(acc[r], -65536.0f, 131072.0f);  // in [65535,196610]
                const unsigned key = ((unsigned)(int)qf << 14) | kbase | (unsigned)base;
                k2 = umin2(k2, umax2(k1, key));
                k1 = umin2(k1, key);
            }
        }
    }
#undef STAGE

    // merge the two half-lanes holding the same x-row
    const unsigned o1 = (unsigned)__shfl_xor((int)k1, 32, 64);
    const unsigned o2 = (unsigned)__shfl_xor((int)k2, 32, 64);
    const unsigned mx = umax2(k1, o1);
    k1 = umin2(k1, o1);
    k2 = umin2(umin2(k2, o2), mx);

    if (lh == 0) {                               // coalesced 32-dword writes
        pk1[(size_t)ks * B + row] = k1;
        pk2[(size_t)ks * B + row] = k2;
    }
}

// ---------------------------------------------------------------------------
// combine + outputs, one wave per row (4 rows/block):
//   lanes 0-7:  candidate a1[split=lane];  lanes 8-15: a2[split=lane-8]
//   each loads its candidate's mask entry; width-16 (min,2nd-min) shfl reduce
//   over effective keys (masked -> ~0). Flags (margin = 5 quanta; error
//   budget: bf16-3term 0.5q + floor-quant 1q + fp32-accum 0.25q -> <=2.5q):
//    (a) no unmasked candidate;
//    (b) near-tie: second_unmasked < best+5q;
//    (c) ANY masked candidate < best+5q (codes hidden beneath a masked
//        candidate are >= it, so an unflagged masked cand >= lim is safe).
// ---------------------------------------------------------------------------
__global__ __launch_bounds__(256) void k_comb(const unsigned* __restrict__ pk1,
                                              const unsigned* __restrict__ pk2,
                                              const int* __restrict__ mask,
                                              const int* __restrict__ training,
                                              const float* __restrict__ xn,
                                              const float* __restrict__ cb,
                                              float* __restrict__ out,
                                              int* __restrict__ fixlist,
                                              int* __restrict__ fixcnt,
                                              int B, int K) {
    const int t = threadIdx.x;
    const int wv = t >> 6, lane = t & 63;
    const int row = blockIdx.x * 4 + wv;
    const int tr = training[0];

    unsigned cand = 0xFFFFFFFFu;                 // this lane's candidate key
    int m = 1;                                   // its mask (1 = kept)
    if (lane < 16) {
        const int c = lane & 7;
        cand = (lane < 8) ? pk1[(size_t)c * B + row] : pk2[(size_t)c * B + row];
        m = (tr == 0) ? 1 : mask[(size_t)row * K + (cand & 16383u)];
    }
    const unsigned eff = (lane < 16 && m != 0) ? cand : 0xFFFFFFFFu;

    // (min, second-min) reduce over the 16 candidate lanes (width 16)
    unsigned b1 = eff, b2 = 0xFFFFFFFFu;
    #pragma unroll
    for (int off = 1; off < 16; off <<= 1) {
        const unsigned oa = (unsigned)__shfl_xor((int)b1, off, 16);
        const unsigned ob = (unsigned)__shfl_xor((int)b2, off, 16);
        const unsigned mx = umax2(b1, oa);
        b1 = umin2(b1, oa);
        b2 = umin2(umin2(b2, ob), mx);
    }
    const unsigned best   = (unsigned)__shfl((int)b1, 0, 64);
    const unsigned second = (unsigned)__shfl((int)b2, 0, 64);
    const unsigned long long lim = (unsigned long long)best + (5ull << 14);

    const bool cflag = (lane < 16) && (m == 0) &&
                       ((unsigned long long)cand < lim);
    const bool flag = __any(cflag) ||
                      (best == 0xFFFFFFFFu) ||
                      ((unsigned long long)second < lim);

    const int bi = (int)(best & 16383u);
    const float zv  = cb[(size_t)bi * D + lane];
    const float xnv = xn[(size_t)row * D + lane];
    out[(size_t)row * D + lane] = xnv + (zv - xnv);                 // z_q
    out[(size_t)B * D + (size_t)row * D + lane] = zv;               // z
    if (lane == 0) {
        out[(size_t)3 * B * D + row] = (float)bi;                   // index
        if (flag) {
            const int p = atomicAdd(fixcnt, 1);
            fixlist[p] = row;
        }
    }
}

// ---------------------------------------------------------------------------
// exact fp32 rescan for flagged rows; overwrites their outputs.
// float4 loads, fmaf chain kept in ascending-d order (same arithmetic).
// ---------------------------------------------------------------------------
__global__ __launch_bounds__(256) void k_fix(const float* __restrict__ xn,
                                             const float* __restrict__ cb,
                                             const int* __restrict__ mask,
                                             const int* __restrict__ training,
                                             const int* __restrict__ fixlist,
                                             const int* __restrict__ fixcnt,
                                             float* __restrict__ out, int B, int K) {
    const int nf = *fixcnt;
    const int tr = training[0];
    __shared__ float sv[256];
    __shared__ int   si[256];
    const int t = threadIdx.x;
    for (int i = blockIdx.x; i < nf; i += gridDim.x) {
        const int row = fixlist[i];
        const float* xr = xn + (size_t)row * D;
        float b1 = FLT_MAX; int i1 = 0;
        for (int k = t; k < K; k += 256) {
            const float4* cr = (const float4*)(cb + (size_t)k * D);
            float s = 0.f;
            #pragma unroll
            for (int g = 0; g < 16; ++g) {
                const float4 c4 = cr[g];
                s = fmaf(xr[g * 4 + 0], c4.x, s);
                s = fmaf(xr[g * 4 + 1], c4.y, s);
                s = fmaf(xr[g * 4 + 2], c4.z, s);
                s = fmaf(xr[g * 4 + 3], c4.w, s);
            }
            const int m = mask[(size_t)row * K + k];
            const float dist = (tr && m == 0) ? 1000000000.0f : -s;
            if (dist < b1) { b1 = dist; i1 = k; }
        }
        sv[t] = b1; si[t] = i1;
        __syncthreads();
        for (int s = 128; s; s >>= 1) {
            if (t < s) {
                const float ov = sv[t + s]; const int oi = si[t + s];
                if (ov < sv[t] || (ov == sv[t] && oi < si[t])) { sv[t] = ov; si[t] = oi; }
            }
            __syncthreads();
        }
        const int bi = si[0];
        if (t < 64) {
            const float zv  = cb[(size_t)bi * D + t];
            const float xnv = xr[t];
            out[(size_t)row * D + t] = xnv + (zv - xnv);
            out[(size_t)B * D + (size_t)row * D + t] = zv;
        }
        if (t == 0) out[(size_t)3 * B * D + row] = (float)bi;
        __syncthreads();
    }
}

extern "C" void kernel_launch(void* const* d_in, const int* in_sizes, int n_in,
                              void* d_out, int out_size, void* d_ws, size_t ws_size,
                              hipStream_t stream) {
    const float* x    = (const float*)d_in[0];
    const float* cbin = (const float*)d_in[1];
    const int* mask   = (const int*)d_in[2];
    const int* train  = (const int*)d_in[3];
    const int B = in_sizes[0] / D;   // 16384
    const int K = in_sizes[1] / D;   // 16384
    float* out = (float*)d_out;
    float* out_xn = out + (size_t)2 * B * D;

    char* w = (char*)d_ws;
    float* cbw          = (float*)w;                               // 4 MB
    unsigned short* xhw = (unsigned short*)(w + (size_t)K * D * 4);
    unsigned short* xlw = xhw + (size_t)B * D;
    unsigned short* chw = xlw + (size_t)B * D;
    unsigned short* clw = chw + (size_t)K * D;
    unsigned* pk1       = (unsigned*)(clw + (size_t)K * D);        // B*8 u32
    unsigned* pk2       = pk1 + (size_t)B * 8;                     // B*8 u32
    int* fixlist        = (int*)(pk2 + (size_t)B * 8);
    int* fixcnt         = fixlist + B;

    k_prep <<<K / 4 + B / 4, 256, 0, stream>>>(cbin, cbw, chw, clw,
                                               x, out_xn, xhw, xlw, fixcnt, K / 4);
    k_mfma <<<(B / 128) * 8, 256, 0, stream>>>(xhw, xlw, chw, clw, pk1, pk2, B, K);
    k_comb <<<B / 4, 256, 0, stream>>>(pk1, pk2, mask, train, out_xn, cbw, out,
                                       fixlist, fixcnt, B, K);
    k_fix  <<<256, 256, 0, stream>>>(out_xn, cbw, mask, train, fixlist, fixcnt,
                                     out, B, K);
}

// Round 22
// 348.930 us; speedup vs baseline: 2.6259x; 2.6259x over previous
//
#include <hip/hip_runtime.h>
#include <math.h>
#include <float.h>

#define EPSV 1e-8f
constexpr int D = 64;

typedef __attribute__((ext_vector_type(8)))  short short8;
typedef __attribute__((ext_vector_type(16))) float f32x16;

static __device__ __forceinline__ unsigned short f2bf(float f) {
    unsigned u = __float_as_uint(f);
    unsigned r = u + 0x7FFFu + ((u >> 16) & 1u);   // round-to-nearest-even
    return (unsigned short)(r >> 16);
}
static __device__ __forceinline__ float bf2f(unsigned short b) {
    return __uint_as_float(((unsigned)b) << 16);
}
static __device__ __forceinline__ unsigned umin2(unsigned a, unsigned b) { return a < b ? a : b; }
static __device__ __forceinline__ unsigned umax2(unsigned a, unsigned b) { return a > b ? a : b; }

// fragment-ready layout: entity panel p=e>>5, k-slot q=k>>3:
//   u16 index = p*2048 + q*256 + (e&31)*8 + (k&7)
static __device__ __forceinline__ size_t fragidx(int e, int k) {
    return (size_t)(e >> 5) * 2048 + (size_t)(k >> 3) * 256 + (e & 31) * 8 + (k & 7);
}

// ---------------------------------------------------------------------------
// prep (fused): blocks [0, K/4) normalize codebook rows; blocks [K/4, ...)
// normalize x rows (xn + hi/lo fragments). Also zeroes fixcnt.
// ---------------------------------------------------------------------------
__global__ __launch_bounds__(256) void k_prep(const float* __restrict__ cbin,
                                              float* __restrict__ cb,
                                              unsigned short* __restrict__ ch,
                                              unsigned short* __restrict__ cl,
                                              const float* __restrict__ xin,
                                              float* __restrict__ xn,
                                              unsigned short* __restrict__ xh,
                                              unsigned short* __restrict__ xl,
                                              int* __restrict__ fixcnt,
                                              int nbcb) {
    const int t = threadIdx.x;
    if (blockIdx.x == 0 && t == 0) *fixcnt = 0;
    const int wv = t >> 6, lane = t & 63;
    if ((int)blockIdx.x < nbcb) {
        const int code = blockIdx.x * 4 + wv;
        float v = cbin[(size_t)code * D + lane];
        float ss = v * v;
        #pragma unroll
        for (int off = 32; off; off >>= 1) ss += __shfl_xor(ss, off, 64);
        const float c1 = v / (sqrtf(ss) + EPSV);
        cb[(size_t)code * D + lane] = c1;
        float ss2 = c1 * c1;
        #pragma unroll
        for (int off = 32; off; off >>= 1) ss2 += __shfl_xor(ss2, off, 64);
        const float c2 = c1 / (sqrtf(ss2) + EPSV);
        const unsigned short h = f2bf(c2);
        const size_t fi = fragidx(code, lane);
        ch[fi] = h;
        cl[fi] = f2bf(c2 - bf2f(h));
    } else {
        const int row = (blockIdx.x - nbcb) * 4 + wv;
        float v = xin[(size_t)row * D + lane];
        float ss = v * v;
        #pragma unroll
        for (int off = 32; off; off >>= 1) ss += __shfl_xor(ss, off, 64);
        const float xv = v / (sqrtf(ss) + EPSV);
        xn[(size_t)row * D + lane] = xv;
        const unsigned short h = f2bf(xv);
        const size_t fi = fragidx(row, lane);
        xh[fi] = h;
        xl[fi] = f2bf(xv - bf2f(h));
    }
}

// ---------------------------------------------------------------------------
// main: 128 rows x 2048 codes per block (32 tiles of 64 codes), 4 waves.
// MASK-FREE: pure GEMM + per-lane top-2 of key=(q<<14)|code (u32-min).
// Swapped MFMA (A=codes, B=x-rows): acc col = x-row -> lane-local argmin.
// Code fragments staged to LDS once per BLOCK (shared by 4 waves ->
// 4x less L2 traffic), double-buffered via global_load_lds.
// ---------------------------------------------------------------------------
__global__ __launch_bounds__(256, 4) void k_mfma(const unsigned short* __restrict__ xh,
                                                 const unsigned short* __restrict__ xl,
                                                 const unsigned short* __restrict__ ch,
                                                 const unsigned short* __restrict__ cl,
                                                 unsigned* __restrict__ pk1,
                                                 unsigned* __restrict__ pk2,
                                                 int B, int K) {
    __shared__ short8 lch[2][2][256];            // 16 KB: [buf][panel][frag]
    __shared__ short8 lcl[2][2][256];            // 16 KB
    const int t = threadIdx.x;
    const int wv = t >> 6, lane = t & 63;
    const int lh = lane >> 5, lm = lane & 31;
    const int ks = (int)(blockIdx.x & 7);        // k-split (XCD-affine slice)
    const int rb = (int)(blockIdx.x >> 3);
    const int lh4 = lh * 4;

    const short8* xh8 = (const short8*)xh;
    const short8* xl8 = (const short8*)xl;
    const short8* ch8 = (const short8*)ch;
    const short8* cl8 = (const short8*)cl;

    const int rp = rb * 4 + wv;                  // this wave's 32-row panel
    const int row = rp * 32 + lm;                // this lane's x-row

    // B fragments (x rows), held for the whole block
    short8 bh[4], bl[4];
    #pragma unroll
    for (int s = 0; s < 4; ++s) {
        const size_t bi = (size_t)rp * 256 + (s * 2 + lh) * 32 + lm;
        bh[s] = xh8[bi];
        bl[s] = xl8[bi];
    }

    // stage tile tt_'s ch/cl fragments (2 panels) into buffer b_
#define STAGE(b_, tt_) do {                                                    \
    const int ct_ = ks * 32 + (tt_);                                           \
    const short8* s0 = ch8 + (size_t)(ct_ * 2 + 0) * 256 + t;                  \
    const short8* s1 = ch8 + (size_t)(ct_ * 2 + 1) * 256 + t;                  \
    const short8* s2 = cl8 + (size_t)(ct_ * 2 + 0) * 256 + t;                  \
    const short8* s3 = cl8 + (size_t)(ct_ * 2 + 1) * 256 + t;                  \
    __builtin_amdgcn_global_load_lds(                                          \
        (const __attribute__((address_space(1))) void*)s0,                     \
        (__attribute__((address_space(3))) void*)(&lch[b_][0][wv * 64]), 16, 0, 0); \
    __builtin_amdgcn_global_load_lds(                                          \
        (const __attribute__((address_space(1))) void*)s1,                     \
        (__attribute__((address_space(3))) void*)(&lch[b_][1][wv * 64]), 16, 0, 0); \
    __builtin_amdgcn_global_load_lds(                                          \
        (const __attribute__((address_space(1))) void*)s2,                     \
        (__attribute__((address_space(3))) void*)(&lcl[b_][0][wv * 64]), 16, 0, 0); \
    __builtin_amdgcn_global_load_lds(                                          \
        (const __attribute__((address_space(1))) void*)s3,                     \
        (__attribute__((address_space(3))) void*)(&lcl[b_][1][wv * 64]), 16, 0, 0); \
} while (0)

    unsigned k1 = 0xFFFFFFFFu, k2 = 0xFFFFFFFFu;

    STAGE(0, 0);

    #pragma unroll 1
    for (int tt = 0; tt < 32; ++tt) {
        __syncthreads();                         // drains stage(tt) (vmcnt)
        if (tt < 31) STAGE((tt + 1) & 1, tt + 1);
        const int bsel = tt & 1;
        const int ct = ks * 32 + tt;             // global 64-code tile id

        #pragma unroll
        for (int p = 0; p < 2; ++p) {
            short8 ah[4], al[4];
            #pragma unroll
            for (int s = 0; s < 4; ++s) {
                const int ai = (s * 2 + lh) * 32 + lm;
                ah[s] = lch[bsel][p][ai];
                al[s] = lcl[bsel][p][ai];
            }
            f32x16 acc;
            #pragma unroll
            for (int i = 0; i < 16; ++i) acc[i] = 0.f;
            #pragma unroll
            for (int s = 0; s < 4; ++s) {
                acc = __builtin_amdgcn_mfma_f32_32x32x16_bf16(ah[s], bh[s], acc, 0, 0, 0);
                acc = __builtin_amdgcn_mfma_f32_32x32x16_bf16(ah[s], bl[s], acc, 0, 0, 0);
                acc = __builtin_amdgcn_mfma_f32_32x32x16_bf16(al[s], bh[s], acc, 0, 0, 0);
            }
            const unsigned kbase = (unsigned)(ct * 64 + p * 32 + lh4);
            #pragma unroll
            for (int r = 0; r < 16; ++r) {
                const int base = (r & 3) + 8 * (r >> 2);              // static
                const float qf = fmaf(acc[r], -65536.0f, 131072.0f);  // in [65535,196610]
                const unsigned key = ((unsigned)(int)qf << 14) | kbase | (unsigned)base;
                k2 = umin2(k2, umax2(k1, key));
                k1 = umin2(k1, key);
            }
        }
    }
#undef STAGE

    // merge the two half-lanes holding the same x-row
    const unsigned o1 = (unsigned)__shfl_xor((int)k1, 32, 64);
    const unsigned o2 = (unsigned)__shfl_xor((int)k2, 32, 64);
    const unsigned mx = umax2(k1, o1);
    k1 = umin2(k1, o1);
    k2 = umin2(umin2(k2, o2), mx);

    if (lh == 0) {                               // coalesced 32-dword writes
        pk1[(size_t)ks * B + row] = k1;
        pk2[(size_t)ks * B + row] = k2;
    }
}

// ---------------------------------------------------------------------------
// combine + outputs, one wave per row (4 rows/block):
//   lanes 0-7:  candidate a1[split=lane];  lanes 8-15: a2[split=lane-8]
//   each loads its candidate's mask entry; width-16 (min,2nd-min) shfl reduce
//   over effective keys (masked -> ~0).
// Flags (margin 5 quanta; bf16-3term 0.5q + floor-quant 1q + accum 0.25q):
//  (a) no unmasked candidate;
//  (b) near-tie among visible: second_unmasked < best+5q;
//  (c') hidden-code bound: min over splits of k2[s] < best+5q.
//      Sound because every non-candidate code of split s has key >= k2[s],
//      INDEPENDENT of mask bits; masked candidates themselves are excluded
//      exactly. (R21's "any masked cand" rule fired on ~10% of rows.)
// ---------------------------------------------------------------------------
__global__ __launch_bounds__(256) void k_comb(const unsigned* __restrict__ pk1,
                                              const unsigned* __restrict__ pk2,
                                              const int* __restrict__ mask,
                                              const int* __restrict__ training,
                                              const float* __restrict__ xn,
                                              const float* __restrict__ cb,
                                              float* __restrict__ out,
                                              int* __restrict__ fixlist,
                                              int* __restrict__ fixcnt,
                                              int B, int K) {
    const int t = threadIdx.x;
    const int wv = t >> 6, lane = t & 63;
    const int row = blockIdx.x * 4 + wv;
    const int tr = training[0];

    unsigned cand = 0xFFFFFFFFu;                 // this lane's candidate key
    int m = 1;                                   // its mask (1 = kept)
    if (lane < 16) {
        const int c = lane & 7;
        cand = (lane < 8) ? pk1[(size_t)c * B + row] : pk2[(size_t)c * B + row];
        m = (tr == 0) ? 1 : mask[(size_t)row * K + (cand & 16383u)];
    }
    const unsigned eff = (lane < 16 && m != 0) ? cand : 0xFFFFFFFFu;
    // per-split k2 for the hidden-code bound (lanes 8-15 hold pk2 values)
    const unsigned hid = (lane >= 8 && lane < 16) ? cand : 0xFFFFFFFFu;

    // (min, second-min) over effective keys + min over hidden bounds
    unsigned b1 = eff, b2 = 0xFFFFFFFFu, hmin = hid;
    #pragma unroll
    for (int off = 1; off < 16; off <<= 1) {
        const unsigned oa = (unsigned)__shfl_xor((int)b1, off, 16);
        const unsigned ob = (unsigned)__shfl_xor((int)b2, off, 16);
        const unsigned oh = (unsigned)__shfl_xor((int)hmin, off, 16);
        const unsigned mx = umax2(b1, oa);
        b1 = umin2(b1, oa);
        b2 = umin2(umin2(b2, ob), mx);
        hmin = umin2(hmin, oh);
    }
    const unsigned best   = (unsigned)__shfl((int)b1, 0, 64);
    const unsigned second = (unsigned)__shfl((int)b2, 0, 64);
    const unsigned hminw  = (unsigned)__shfl((int)hmin, 0, 64);
    const unsigned long long lim = (unsigned long long)best + (5ull << 14);

    const bool flag = (best == 0xFFFFFFFFu) ||
                      ((unsigned long long)second < lim) ||
                      ((unsigned long long)hminw < lim);

    const int bi = (int)(best & 16383u);
    const float zv  = cb[(size_t)bi * D + lane];
    const float xnv = xn[(size_t)row * D + lane];
    out[(size_t)row * D + lane] = xnv + (zv - xnv);                 // z_q
    out[(size_t)B * D + (size_t)row * D + lane] = zv;               // z
    if (lane == 0) {
        out[(size_t)3 * B * D + row] = (float)bi;                   // index
        if (flag) {
            const int p = atomicAdd(fixcnt, 1);
            fixlist[p] = row;
        }
    }
}

// ---------------------------------------------------------------------------
// exact fp32 rescan for flagged rows; overwrites their outputs.
// float4 loads, fmaf chain in ascending-d order (same arithmetic).
// ---------------------------------------------------------------------------
__global__ __launch_bounds__(256) void k_fix(const float* __restrict__ xn,
                                             const float* __restrict__ cb,
                                             const int* __restrict__ mask,
                                             const int* __restrict__ training,
                                             const int* __restrict__ fixlist,
                                             const int* __restrict__ fixcnt,
                                             float* __restrict__ out, int B, int K) {
    const int nf = *fixcnt;
    const int tr = training[0];
    __shared__ float sv[256];
    __shared__ int   si[256];
    const int t = threadIdx.x;
    for (int i = blockIdx.x; i < nf; i += gridDim.x) {
        const int row = fixlist[i];
        const float* xr = xn + (size_t)row * D;
        float b1 = FLT_MAX; int i1 = 0;
        for (int k = t; k < K; k += 256) {
            const float4* cr = (const float4*)(cb + (size_t)k * D);
            float s = 0.f;
            #pragma unroll
            for (int g = 0; g < 16; ++g) {
                const float4 c4 = cr[g];
                s = fmaf(xr[g * 4 + 0], c4.x, s);
                s = fmaf(xr[g * 4 + 1], c4.y, s);
                s = fmaf(xr[g * 4 + 2], c4.z, s);
                s = fmaf(xr[g * 4 + 3], c4.w, s);
            }
            const int m = mask[(size_t)row * K + k];
            const float dist = (tr && m == 0) ? 1000000000.0f : -s;
            if (dist < b1) { b1 = dist; i1 = k; }
        }
        sv[t] = b1; si[t] = i1;
        __syncthreads();
        for (int s = 128; s; s >>= 1) {
            if (t < s) {
                const float ov = sv[t + s]; const int oi = si[t + s];
                if (ov < sv[t] || (ov == sv[t] && oi < si[t])) { sv[t] = ov; si[t] = oi; }
            }
            __syncthreads();
        }
        const int bi = si[0];
        if (t < 64) {
            const float zv  = cb[(size_t)bi * D + t];
            const float xnv = xr[t];
            out[(size_t)row * D + t] = xnv + (zv - xnv);
            out[(size_t)B * D + (size_t)row * D + t] = zv;
        }
        if (t == 0) out[(size_t)3 * B * D + row] = (float)bi;
        __syncthreads();
    }
}

extern "C" void kernel_launch(void* const* d_in, const int* in_sizes, int n_in,
                              void* d_out, int out_size, void* d_ws, size_t ws_size,
                              hipStream_t stream) {
    const float* x    = (const float*)d_in[0];
    const float* cbin = (const float*)d_in[1];
    const int* mask   = (const int*)d_in[2];
    const int* train  = (const int*)d_in[3];
    const int B = in_sizes[0] / D;   // 16384
    const int K = in_sizes[1] / D;   // 16384
    float* out = (float*)d_out;
    float* out_xn = out + (size_t)2 * B * D;

    char* w = (char*)d_ws;
    float* cbw          = (float*)w;                               // 4 MB
    unsigned short* xhw = (unsigned short*)(w + (size_t)K * D * 4);
    unsigned short* xlw = xhw + (size_t)B * D;
    unsigned short* chw = xlw + (size_t)B * D;
    unsigned short* clw = chw + (size_t)K * D;
    unsigned* pk1       = (unsigned*)(clw + (size_t)K * D);        // B*8 u32
    unsigned* pk2       = pk1 + (size_t)B * 8;                     // B*8 u32
    int* fixlist        = (int*)(pk2 + (size_t)B * 8);
    int* fixcnt         = fixlist + B;

    k_prep <<<K / 4 + B / 4, 256, 0, stream>>>(cbin, cbw, chw, clw,
                                               x, out_xn, xhw, xlw, fixcnt, K / 4);
    k_mfma <<<(B / 128) * 8, 256, 0, stream>>>(xhw, xlw, chw, clw, pk1, pk2, B, K);
    k_comb <<<B / 4, 256, 0, stream>>>(pk1, pk2, mask, train, out_xn, cbw, out,
                                       fixlist, fixcnt, B, K);
    k_fix  <<<256, 256, 0, stream>>>(out_xn, cbw, mask, train, fixlist, fixcnt,
                                     out, B, K);
}

// Round 23
// 236.578 us; speedup vs baseline: 3.8730x; 1.4749x over previous
//
#include <hip/hip_runtime.h>
#include <math.h>
#include <float.h>

#define EPSV 1e-8f
constexpr int D = 64;

typedef __attribute__((ext_vector_type(8)))  short short8;
typedef __attribute__((ext_vector_type(16))) float f32x16;

static __device__ __forceinline__ unsigned short f2bf(float f) {
    unsigned u = __float_as_uint(f);
    unsigned r = u + 0x7FFFu + ((u >> 16) & 1u);   // round-to-nearest-even
    return (unsigned short)(r >> 16);
}
static __device__ __forceinline__ float bf2f(unsigned short b) {
    return __uint_as_float(((unsigned)b) << 16);
}
static __device__ __forceinline__ unsigned umin2(unsigned a, unsigned b) { return a < b ? a : b; }
static __device__ __forceinline__ unsigned umax2(unsigned a, unsigned b) { return a > b ? a : b; }

// fragment-ready layout: entity panel p=e>>5, k-slot q=k>>3:
//   u16 index = p*2048 + q*256 + (e&31)*8 + (k&7)
static __device__ __forceinline__ size_t fragidx(int e, int k) {
    return (size_t)(e >> 5) * 2048 + (size_t)(k >> 3) * 256 + (e & 31) * 8 + (k & 7);
}

// ---------------------------------------------------------------------------
// prep (fused): blocks [0, K/4) normalize codebook rows; blocks [K/4, ...)
// normalize x rows (xn + hi/lo fragments). Also zeroes fixcnt.
// ---------------------------------------------------------------------------
__global__ __launch_bounds__(256) void k_prep(const float* __restrict__ cbin,
                                              float* __restrict__ cb,
                                              unsigned short* __restrict__ ch,
                                              unsigned short* __restrict__ cl,
                                              const float* __restrict__ xin,
                                              float* __restrict__ xn,
                                              unsigned short* __restrict__ xh,
                                              unsigned short* __restrict__ xl,
                                              int* __restrict__ fixcnt,
                                              int nbcb) {
    const int t = threadIdx.x;
    if (blockIdx.x == 0 && t == 0) *fixcnt = 0;
    const int wv = t >> 6, lane = t & 63;
    if ((int)blockIdx.x < nbcb) {
        const int code = blockIdx.x * 4 + wv;
        float v = cbin[(size_t)code * D + lane];
        float ss = v * v;
        #pragma unroll
        for (int off = 32; off; off >>= 1) ss += __shfl_xor(ss, off, 64);
        const float c1 = v / (sqrtf(ss) + EPSV);
        cb[(size_t)code * D + lane] = c1;
        float ss2 = c1 * c1;
        #pragma unroll
        for (int off = 32; off; off >>= 1) ss2 += __shfl_xor(ss2, off, 64);
        const float c2 = c1 / (sqrtf(ss2) + EPSV);
        const unsigned short h = f2bf(c2);
        const size_t fi = fragidx(code, lane);
        ch[fi] = h;
        cl[fi] = f2bf(c2 - bf2f(h));
    } else {
        const int row = (blockIdx.x - nbcb) * 4 + wv;
        float v = xin[(size_t)row * D + lane];
        float ss = v * v;
        #pragma unroll
        for (int off = 32; off; off >>= 1) ss += __shfl_xor(ss, off, 64);
        const float xv = v / (sqrtf(ss) + EPSV);
        xn[(size_t)row * D + lane] = xv;
        const unsigned short h = f2bf(xv);
        const size_t fi = fragidx(row, lane);
        xh[fi] = h;
        xl[fi] = f2bf(xv - bf2f(h));
    }
}

// ---------------------------------------------------------------------------
// main: 128 rows x 2048 codes per block (32 tiles of 64 codes), 4 waves.
// MASK-FREE: pure GEMM + per-lane top-2 of key=(q<<14)|code (u32-min).
// Swapped MFMA (A=codes, B=x-rows): acc col = x-row -> lane-local argmin.
// Code fragments staged to LDS once per BLOCK (shared by 4 waves ->
// 4x less L2 traffic), double-buffered via global_load_lds.
// ---------------------------------------------------------------------------
__global__ __launch_bounds__(256, 4) void k_mfma(const unsigned short* __restrict__ xh,
                                                 const unsigned short* __restrict__ xl,
                                                 const unsigned short* __restrict__ ch,
                                                 const unsigned short* __restrict__ cl,
                                                 unsigned* __restrict__ pk1,
                                                 unsigned* __restrict__ pk2,
                                                 int B, int K) {
    __shared__ short8 lch[2][2][256];            // 16 KB: [buf][panel][frag]
    __shared__ short8 lcl[2][2][256];            // 16 KB
    const int t = threadIdx.x;
    const int wv = t >> 6, lane = t & 63;
    const int lh = lane >> 5, lm = lane & 31;
    const int ks = (int)(blockIdx.x & 7);        // k-split (XCD-affine slice)
    const int rb = (int)(blockIdx.x >> 3);
    const int lh4 = lh * 4;

    const short8* xh8 = (const short8*)xh;
    const short8* xl8 = (const short8*)xl;
    const short8* ch8 = (const short8*)ch;
    const short8* cl8 = (const short8*)cl;

    const int rp = rb * 4 + wv;                  // this wave's 32-row panel
    const int row = rp * 32 + lm;                // this lane's x-row

    // B fragments (x rows), held for the whole block
    short8 bh[4], bl[4];
    #pragma unroll
    for (int s = 0; s < 4; ++s) {
        const size_t bi = (size_t)rp * 256 + (s * 2 + lh) * 32 + lm;
        bh[s] = xh8[bi];
        bl[s] = xl8[bi];
    }

    // stage tile tt_'s ch/cl fragments (2 panels) into buffer b_
#define STAGE(b_, tt_) do {                                                    \
    const int ct_ = ks * 32 + (tt_);                                           \
    const short8* s0 = ch8 + (size_t)(ct_ * 2 + 0) * 256 + t;                  \
    const short8* s1 = ch8 + (size_t)(ct_ * 2 + 1) * 256 + t;                  \
    const short8* s2 = cl8 + (size_t)(ct_ * 2 + 0) * 256 + t;                  \
    const short8* s3 = cl8 + (size_t)(ct_ * 2 + 1) * 256 + t;                  \
    __builtin_amdgcn_global_load_lds(                                          \
        (const __attribute__((address_space(1))) void*)s0,                     \
        (__attribute__((address_space(3))) void*)(&lch[b_][0][wv * 64]), 16, 0, 0); \
    __builtin_amdgcn_global_load_lds(                                          \
        (const __attribute__((address_space(1))) void*)s1,                     \
        (__attribute__((address_space(3))) void*)(&lch[b_][1][wv * 64]), 16, 0, 0); \
    __builtin_amdgcn_global_load_lds(                                          \
        (const __attribute__((address_space(1))) void*)s2,                     \
        (__attribute__((address_space(3))) void*)(&lcl[b_][0][wv * 64]), 16, 0, 0); \
    __builtin_amdgcn_global_load_lds(                                          \
        (const __attribute__((address_space(1))) void*)s3,                     \
        (__attribute__((address_space(3))) void*)(&lcl[b_][1][wv * 64]), 16, 0, 0); \
} while (0)

    unsigned k1 = 0xFFFFFFFFu, k2 = 0xFFFFFFFFu;

    STAGE(0, 0);

    #pragma unroll 1
    for (int tt = 0; tt < 32; ++tt) {
        __syncthreads();                         // drains stage(tt) (vmcnt)
        if (tt < 31) STAGE((tt + 1) & 1, tt + 1);
        const int bsel = tt & 1;
        const int ct = ks * 32 + tt;             // global 64-code tile id

        #pragma unroll
        for (int p = 0; p < 2; ++p) {
            short8 ah[4], al[4];
            #pragma unroll
            for (int s = 0; s < 4; ++s) {
                const int ai = (s * 2 + lh) * 32 + lm;
                ah[s] = lch[bsel][p][ai];
                al[s] = lcl[bsel][p][ai];
            }
            f32x16 acc;
            #pragma unroll
            for (int i = 0; i < 16; ++i) acc[i] = 0.f;
            #pragma unroll
            for (int s = 0; s < 4; ++s) {
                acc = __builtin_amdgcn_mfma_f32_32x32x16_bf16(ah[s], bh[s], acc, 0, 0, 0);
                acc = __builtin_amdgcn_mfma_f32_32x32x16_bf16(ah[s], bl[s], acc, 0, 0, 0);
                acc = __builtin_amdgcn_mfma_f32_32x32x16_bf16(al[s], bh[s], acc, 0, 0, 0);
            }
            const unsigned kbase = (unsigned)(ct * 64 + p * 32 + lh4);
            #pragma unroll
            for (int r = 0; r < 16; ++r) {
                const int base = (r & 3) + 8 * (r >> 2);              // static
                const float qf = fmaf(acc[r], -65536.0f, 131072.0f);  // in [65535,196610]
                const unsigned key = ((unsigned)(int)qf << 14) | kbase | (unsigned)base;
                k2 = umin2(k2, umax2(k1, key));
                k1 = umin2(k1, key);
            }
        }
    }
#undef STAGE

    // merge the two half-lanes holding the same x-row
    const unsigned o1 = (unsigned)__shfl_xor((int)k1, 32, 64);
    const unsigned o2 = (unsigned)__shfl_xor((int)k2, 32, 64);
    const unsigned mx = umax2(k1, o1);
    k1 = umin2(k1, o1);
    k2 = umin2(umin2(k2, o2), mx);

    if (lh == 0) {                               // coalesced 32-dword writes
        pk1[(size_t)ks * B + row] = k1;
        pk2[(size_t)ks * B + row] = k2;
    }
}

// ---------------------------------------------------------------------------
// combine + outputs, one wave per row (4 rows/block):
//   lanes 0-7:  candidate a1[split=lane];  lanes 8-15: a2[split=lane-8]
//   each loads its candidate's mask entry; width-16 (min,2nd-min) shfl reduce
//   over effective keys (masked -> ~0). Flags: (a) no unmasked candidate,
//   (b) second < best+10q, (c) both-masked split with k2 < best+10q.
//   All cross-lane shuffles run with the full wave active; predicates after.
// ---------------------------------------------------------------------------
__global__ __launch_bounds__(256) void k_comb(const unsigned* __restrict__ pk1,
                                              const unsigned* __restrict__ pk2,
                                              const int* __restrict__ mask,
                                              const int* __restrict__ training,
                                              const float* __restrict__ xn,
                                              const float* __restrict__ cb,
                                              float* __restrict__ out,
                                              int* __restrict__ fixlist,
                                              int* __restrict__ fixcnt,
                                              int B, int K) {
    const int t = threadIdx.x;
    const int wv = t >> 6, lane = t & 63;
    const int row = blockIdx.x * 4 + wv;
    const int tr = training[0];

    unsigned cand = 0xFFFFFFFFu;                 // this lane's candidate key
    int m = 1;                                   // its mask (1 = kept)
    if (lane < 16) {
        const int c = lane & 7;
        cand = (lane < 8) ? pk1[(size_t)c * B + row] : pk2[(size_t)c * B + row];
        m = (tr == 0) ? 1 : mask[(size_t)row * K + (cand & 16383u)];
    }
    const unsigned eff = (lane < 16 && m != 0) ? cand : 0xFFFFFFFFu;

    // (min, second-min) reduce over the 16 candidate lanes (width 16)
    unsigned b1 = eff, b2 = 0xFFFFFFFFu;
    #pragma unroll
    for (int off = 1; off < 16; off <<= 1) {
        const unsigned oa = (unsigned)__shfl_xor((int)b1, off, 16);
        const unsigned ob = (unsigned)__shfl_xor((int)b2, off, 16);
        const unsigned mx = umax2(b1, oa);
        b1 = umin2(b1, oa);
        b2 = umin2(umin2(b2, ob), mx);
    }
    const unsigned best   = (unsigned)__shfl((int)b1, 0, 64);
    const unsigned second = (unsigned)__shfl((int)b2, 0, 64);
    const unsigned long long lim = (unsigned long long)best + (10ull << 14);

    // hidden-risk: split's both candidates masked AND its k2 < lim
    const int mo        = __shfl_xor(m, 8, 16);          // partner's mask
    const unsigned a2v  = (unsigned)__shfl_xor((int)cand, 8, 16);
    const bool cflag = (lane < 8) && (m == 0) && (mo == 0) &&
                       ((unsigned long long)a2v < lim);
    const bool flag = __any(cflag) ||
                      (best == 0xFFFFFFFFu) ||
                      ((unsigned long long)second < lim);

    const int bi = (int)(best & 16383u);
    const float zv  = cb[(size_t)bi * D + lane];
    const float xnv = xn[(size_t)row * D + lane];
    out[(size_t)row * D + lane] = xnv + (zv - xnv);                 // z_q
    out[(size_t)B * D + (size_t)row * D + lane] = zv;               // z
    if (lane == 0) {
        out[(size_t)3 * B * D + row] = (float)bi;                   // index
        if (flag) {
            const int p = atomicAdd(fixcnt, 1);
            fixlist[p] = row;
        }
    }
}

// ---------------------------------------------------------------------------
// exact fp32 rescan for flagged rows; overwrites their outputs
// ---------------------------------------------------------------------------
__global__ __launch_bounds__(256) void k_fix(const float* __restrict__ xn,
                                             const float* __restrict__ cb,
                                             const int* __restrict__ mask,
                                             const int* __restrict__ training,
                                             const int* __restrict__ fixlist,
                                             const int* __restrict__ fixcnt,
                                             float* __restrict__ out, int B, int K) {
    const int nf = *fixcnt;
    const int tr = training[0];
    __shared__ float sv[256];
    __shared__ int   si[256];
    const int t = threadIdx.x;
    for (int i = blockIdx.x; i < nf; i += gridDim.x) {
        const int row = fixlist[i];
        const float* xr = xn + (size_t)row * D;
        float b1 = FLT_MAX; int i1 = 0;
        for (int k = t; k < K; k += 256) {
            const float* cr = cb + (size_t)k * D;
            float s = 0.f;
            #pragma unroll
            for (int d = 0; d < D; ++d) s = fmaf(xr[d], cr[d], s);
            const int m = mask[(size_t)row * K + k];
            const float dist = (tr && m == 0) ? 1000000000.0f : -s;
            if (dist < b1) { b1 = dist; i1 = k; }
        }
        sv[t] = b1; si[t] = i1;
        __syncthreads();
        for (int s = 128; s; s >>= 1) {
            if (t < s) {
                const float ov = sv[t + s]; const int oi = si[t + s];
                if (ov < sv[t] || (ov == sv[t] && oi < si[t])) { sv[t] = ov; si[t] = oi; }
            }
            __syncthreads();
        }
        const int bi = si[0];
        if (t < 64) {
            const float zv  = cb[(size_t)bi * D + t];
            const float xnv = xr[t];
            out[(size_t)row * D + t] = xnv + (zv - xnv);
            out[(size_t)B * D + (size_t)row * D + t] = zv;
        }
        if (t == 0) out[(size_t)3 * B * D + row] = (float)bi;
        __syncthreads();
    }
}

extern "C" void kernel_launch(void* const* d_in, const int* in_sizes, int n_in,
                              void* d_out, int out_size, void* d_ws, size_t ws_size,
                              hipStream_t stream) {
    const float* x    = (const float*)d_in[0];
    const float* cbin = (const float*)d_in[1];
    const int* mask   = (const int*)d_in[2];
    const int* train  = (const int*)d_in[3];
    const int B = in_sizes[0] / D;   // 16384
    const int K = in_sizes[1] / D;   // 16384
    float* out = (float*)d_out;
    float* out_xn = out + (size_t)2 * B * D;

    char* w = (char*)d_ws;
    float* cbw          = (float*)w;                               // 4 MB
    unsigned short* xhw = (unsigned short*)(w + (size_t)K * D * 4);
    unsigned short* xlw = xhw + (size_t)B * D;
    unsigned short* chw = xlw + (size_t)B * D;
    unsigned short* clw = chw + (size_t)K * D;
    unsigned* pk1       = (unsigned*)(clw + (size_t)K * D);        // B*8 u32
    unsigned* pk2       = pk1 + (size_t)B * 8;                     // B*8 u32
    int* fixlist        = (int*)(pk2 + (size_t)B * 8);
    int* fixcnt         = fixlist + B;

    k_prep <<<K / 4 + B / 4, 256, 0, stream>>>(cbin, cbw, chw, clw,
                                               x, out_xn, xhw, xlw, fixcnt, K / 4);
    k_mfma <<<(B / 128) * 8, 256, 0, stream>>>(xhw, xlw, chw, clw, pk1, pk2, B, K);
    k_comb <<<B / 4, 256, 0, stream>>>(pk1, pk2, mask, train, out_xn, cbw, out,
                                       fixlist, fixcnt, B, K);
    k_fix  <<<256, 256, 0, stream>>>(out_xn, cbw, mask, train, fixlist, fixcnt,
                                     out, B, K);
}